// Round 2
// baseline (11124.512 us; speedup 1.0000x reference)
//
#include <hip/hip_runtime.h>
#include <cstdint>
#include <cstddef>
#include <type_traits>
#include <utility>

typedef unsigned short u16;
typedef short short8 __attribute__((ext_vector_type(8)));
typedef __bf16 bf16x8 __attribute__((ext_vector_type(8)));
typedef float float4v __attribute__((ext_vector_type(4)));

// ---------- bf16 <-> f32 ----------
__device__ __forceinline__ float bf2f(u16 u) {
  union { uint32_t i; float f; } v; v.i = ((uint32_t)u) << 16; return v.f;
}
__device__ __forceinline__ u16 f2bf(float f) {
  union { uint32_t i; float f; } v; v.f = f;
  uint32_t u = v.i;
  return (u16)((u + 0x7FFFu + ((u >> 16) & 1u)) >> 16);
}

// ---------- fast transcendentals (saturate cleanly at +-inf) ----------
__device__ __forceinline__ float fsig(float x) {
  float e = __expf(-x);
  return __builtin_amdgcn_rcpf(1.0f + e);
}
__device__ __forceinline__ float ftanh(float x) {
  float e = __expf(2.0f * x);
  return 1.0f - 2.0f * __builtin_amdgcn_rcpf(e + 1.0f);
}

// ---------- MFMA wrapper: works whether builtin takes short8 or bf16x8 ----------
template <class V, class = void> struct MfmaTakesShort : std::false_type {};
template <class V>
struct MfmaTakesShort<V, std::void_t<decltype(__builtin_amdgcn_mfma_f32_16x16x32_bf16(
    std::declval<V>(), std::declval<V>(), std::declval<float4v>(), 0, 0, 0))>>
    : std::true_type {};

template <bool UseShort> struct MF {
  template <class V>
  static __device__ __forceinline__ float4v run(V a, V b, float4v c) {
    return __builtin_amdgcn_mfma_f32_16x16x32_bf16(a, b, c, 0, 0, 0);
  }
};
template <> struct MF<false> {
  template <class V>
  static __device__ __forceinline__ float4v run(V a, V b, float4v c) {
    return __builtin_amdgcn_mfma_f32_16x16x32_bf16(
        __builtin_bit_cast(bf16x8, a), __builtin_bit_cast(bf16x8, b), c, 0, 0, 0);
  }
};
__device__ __forceinline__ float4v mfma_bf16(short8 a, short8 b, float4v c) {
  return MF<MfmaTakesShort<short8>::value>::run(a, b, c);
}

// ============================================================================
// Weight conversion: f32 [2048][Kin] -> bf16 [2048][512], zero-padded
// ============================================================================
__global__ void k_cvt_wih(const float* __restrict__ w, u16* __restrict__ o, int Kin) {
  int id = blockIdx.x * 256 + threadIdx.x;   // 2048*512 total
  int n = id >> 9, k = id & 511;
  o[id] = (k < Kin) ? f2bf(w[(long)n * Kin + k]) : (u16)0;
}

// f32 -> bf16 straight convert (w_hh: 2*1024*256 = 524288 elems)
__global__ void k_cvt_whh(const float* __restrict__ w, u16* __restrict__ o) {
  int id = blockIdx.x * 256 + threadIdx.x;
  o[id] = f2bf(w[id]);
}

// ============================================================================
// proj[v][k][nf] = sum_cd emb_char[v][cd] * conv_w[nf][cd][k]   (f32 in, bf16 out)
// ============================================================================
__global__ void k_proj(const float* __restrict__ ec, const float* __restrict__ cw,
                       u16* __restrict__ proj) {
  int v = blockIdx.x, idx = threadIdx.x;
  if (idx >= 300) return;
  int k = idx / 100, nf = idx % 100;
  float s = 0.f;
  for (int cd = 0; cd < 100; cd++)
    s += ec[v * 100 + cd] * cw[(nf * 100 + cd) * 3 + k];
  proj[v * 300 + k * 100 + nf] = f2bf(s);
}

// ============================================================================
// word + pos embedding gather into bf16 x (cols 0..299 word, 400..499 pos,
// 500..511 zero). Char features (300..399) filled by k_charconv.
// ============================================================================
__global__ void k_embed(const int* __restrict__ iw, const int* __restrict__ ip,
                        const float* __restrict__ ew, const float* __restrict__ ep,
                        u16* __restrict__ x) {
  int row = blockIdx.x, j = threadIdx.x;
  u16 v;
  if (j < 300) v = f2bf(ew[(long)iw[row] * 300 + j]);
  else if (j < 400) return;
  else if (j < 500) v = f2bf(ep[ip[row] * 100 + (j - 400)]);
  else v = 0;
  x[row * 512 + j] = v;
}

// ============================================================================
// char conv via proj table in LDS: out[nf] = tanh(b + max_p sum_k proj)
// ============================================================================
__global__ __launch_bounds__(128) void k_charconv(const int* __restrict__ ic,
                                                  const u16* __restrict__ proj,
                                                  const float* __restrict__ cb,
                                                  u16* __restrict__ x) {
  __shared__ u16 pl[30000];
  __shared__ int ids[20];
  int tid = threadIdx.x;
  for (int i = tid; i < 15000; i += 128)
    ((uint32_t*)pl)[i] = ((const uint32_t*)proj)[i];
  float bias = (tid < 100) ? cb[tid] : 0.f;
  for (int r = 0; r < 16; r++) {
    int row = blockIdx.x * 16 + r;
    __syncthreads();  // covers pl load on first iter; protects ids reuse
    if (tid < 20) ids[tid] = ic[row * 20 + tid];
    __syncthreads();
    if (tid < 100) {
      float mx = -1e30f;
      for (int p = 0; p < 22; p++) {
        float s = 0.f;
#pragma unroll
        for (int k = 0; k < 3; k++) {
          int q = p + k - 2;
          if (q >= 0 && q < 20) s += bf2f(pl[ids[q] * 300 + k * 100 + tid]);
        }
        mx = fmaxf(mx, s);
      }
      x[row * 512 + 300 + tid] = f2bf(ftanh(mx + bias));
    }
  }
}

// ============================================================================
// GEMM  C[16384 x 2048] = A[16384 x 512](bf16) @ B[2048 x 512]^T + bias(f32)
// 128x128 tile, BK=64, 4 waves, 16x16x32 MFMA. C fp32 (tier A) or bf16 (tier B).
// ============================================================================
template <bool GXF32>
__global__ __launch_bounds__(256) void k_gemm(const u16* __restrict__ A,
                                              const u16* __restrict__ Bm,
                                              const float* __restrict__ bias,
                                              void* __restrict__ Cv) {
  __shared__ u16 lA[128 * 64];
  __shared__ u16 lB[128 * 64];
  int tid = threadIdx.x;
  int w = tid >> 6, l = tid & 63, q = l >> 4, c16 = l & 15;
  int wm = w >> 1, wn = w & 1;
  int m0 = blockIdx.y * 128, n0 = blockIdx.x * 128;
  float4v acc[4][4];
#pragma unroll
  for (int i = 0; i < 4; i++)
#pragma unroll
    for (int j = 0; j < 4; j++) acc[i][j] = (float4v){0.f, 0.f, 0.f, 0.f};

  for (int kk = 0; kk < 512; kk += 64) {
    __syncthreads();
#pragma unroll
    for (int j = 0; j < 4; j++) {
      int idx = j * 256 + tid;
      int m = idx >> 3, k8 = (idx & 7) * 8;
      *(short8*)(lA + idx * 8) = *(const short8*)(A + (long)(m0 + m) * 512 + kk + k8);
      *(short8*)(lB + idx * 8) = *(const short8*)(Bm + (long)(n0 + m) * 512 + kk + k8);
    }
    __syncthreads();
#pragma unroll
    for (int kt = 0; kt < 2; kt++) {
      short8 af[4], bfv[4];
#pragma unroll
      for (int mt = 0; mt < 4; mt++)
        af[mt] = *(const short8*)(lA + (wm * 64 + mt * 16 + c16) * 64 + kt * 32 + q * 8);
#pragma unroll
      for (int nt = 0; nt < 4; nt++)
        bfv[nt] = *(const short8*)(lB + (wn * 64 + nt * 16 + c16) * 64 + kt * 32 + q * 8);
#pragma unroll
      for (int mt = 0; mt < 4; mt++)
#pragma unroll
        for (int nt = 0; nt < 4; nt++)
          acc[mt][nt] = mfma_bf16(af[mt], bfv[nt], acc[mt][nt]);
    }
  }
#pragma unroll
  for (int mt = 0; mt < 4; mt++)
#pragma unroll
    for (int nt = 0; nt < 4; nt++) {
      int ng = n0 + wn * 64 + nt * 16 + c16;
      float bv = bias[ng];
#pragma unroll
      for (int r = 0; r < 4; r++) {
        long mg = m0 + wm * 64 + mt * 16 + q * 4 + r;
        float val = acc[mt][nt][r] + bv;
        if constexpr (GXF32) ((float*)Cv)[mg * 2048 + ng] = val;
        else ((u16*)Cv)[mg * 2048 + ng] = f2bf(val);
      }
    }
}

// ============================================================================
// LSTM recurrence. 8 blocks = 4 batch-groups x 2 dirs, 512 thr (8 waves).
// Each block owns 16 batch rows end-to-end: zero cross-WG sync.
// w_hh (1024x256 bf16 = 512KB): per wave 46 B-frags in VGPRs + 18 in LDS.
// Two passes over gate-column halves (hti) keep live acc at 4 float4.
// ============================================================================
template <bool GXF32, bool OUTF32>
__global__ __launch_bounds__(512, 2) void k_recur(const void* __restrict__ gxv,
                                                  const u16* __restrict__ whh,
                                                  const float* __restrict__ mask,
                                                  void* __restrict__ outv) {
  __shared__ u16 ldsB[8 * 18 * 64 * 8];  // 147456 B
  __shared__ u16 hls[16 * 264];          // 8448 B
  constexpr int NREG = 46;
  int tid = threadIdx.x;
  int w = tid >> 6, l = tid & 63, q = l >> 4, c16 = l & 15;
  int bg = blockIdx.x & 3, d = blockIdx.x >> 2;
  int b0 = bg * 16;
  const u16* Wd = whh + d * (1024 * 256);

  for (int i = tid; i < 16 * 264; i += 512) hls[i] = 0;

  // B fragments: id = (g*2+hti)*8 + kt; coltile nt = g*16 + 2w + hti
  short8 Breg[NREG];
#pragma unroll
  for (int f = 0; f < 8; f++) {
    int nt = (f >> 1) * 16 + 2 * w + (f & 1);
#pragma unroll
    for (int kt = 0; kt < 8; kt++) {
      int id = f * 8 + kt;
      short8 v = *(const short8*)(Wd + (nt * 16 + c16) * 256 + kt * 32 + q * 8);
      if (id < NREG) Breg[id] = v;
      else *(short8*)(ldsB + ((w * 18 + (id - NREG)) * 64 + l) * 8) = v;
    }
  }
  float c_[2][4], hp[2][4], hn_save[2][4];
#pragma unroll
  for (int i = 0; i < 2; i++)
#pragma unroll
    for (int r = 0; r < 4; r++) { c_[i][r] = 0.f; hp[i][r] = 0.f; }
  __syncthreads();

  const float* gxf = (const float*)gxv;
  const u16* gxh = (const u16*)gxv;
  float* outf = (float*)outv;
  u16* outh = (u16*)outv;

#pragma unroll 1
  for (int s = 0; s < 256; s++) {
    int t = d ? (255 - s) : s;
    float m4[4];
#pragma unroll
    for (int r = 0; r < 4; r++) m4[r] = mask[(b0 + q * 4 + r) * 256 + t];

#pragma unroll 1
    for (int hti = 0; hti < 2; hti++) {
      float4v acc[4];
      // acc init = gx: D/C layout row = q*4+r (batch), col = c16
#pragma unroll
      for (int g = 0; g < 4; g++) {
        int n = ((g * 16 + 2 * w + hti) * 16 + c16) + d * 1024;
#pragma unroll
        for (int r = 0; r < 4; r++) {
          long mrow = (long)((b0 + q * 4 + r) * 256 + t);
          acc[g][r] = GXF32 ? gxf[mrow * 2048 + n] : bf2f(gxh[mrow * 2048 + n]);
        }
      }
      // gates += h @ w_hh^T
#pragma unroll
      for (int kt = 0; kt < 8; kt++) {
        short8 a = *(const short8*)(hls + c16 * 264 + kt * 32 + q * 8);
#pragma unroll
        for (int g = 0; g < 4; g++) {
          int id = (g * 2 + hti) * 8 + kt;
          short8 bb = (id < NREG) ? Breg[id]
                                  : *(const short8*)(ldsB + ((w * 18 + (id - NREG)) * 64 + l) * 8);
          acc[g] = mfma_bf16(a, bb, acc[g]);
        }
      }
#pragma unroll
      for (int r = 0; r < 4; r++) {
        float iv = fsig(acc[0][r]);
        float fv = fsig(acc[1][r]);
        float gv = ftanh(acc[2][r]);
        float ov = fsig(acc[3][r]);
        float cn = fv * c_[hti][r] + iv * gv;
        float hn = ov * ftanh(cn);
        float mt = m4[r];
        hn = mt * hn + (1.f - mt) * hp[hti][r];
        cn = mt * cn + (1.f - mt) * c_[hti][r];
        c_[hti][r] = cn;
        hp[hti][r] = hn;
        hn_save[hti][r] = hn;
        int row = b0 + q * 4 + r;
        int colg = (2 * w + hti) * 16 + c16;
        long oidx = ((long)(row * 256 + t)) * 512 + d * 256 + colg;
        if constexpr (OUTF32) outf[oidx] = hn;
        else outh[oidx] = f2bf(hn);
      }
    }
    __syncthreads();  // all hls reads (both passes, all waves) complete
#pragma unroll
    for (int hti = 0; hti < 2; hti++)
#pragma unroll
      for (int r = 0; r < 4; r++)
        hls[(q * 4 + r) * 264 + (2 * w + hti) * 16 + c16] = f2bf(hn_save[hti][r]);
    __syncthreads();  // h visible before next step reads
  }
}

// ============================================================================
extern "C" void kernel_launch(void* const* d_in, const int* in_sizes, int n_in,
                              void* d_out, int out_size, void* d_ws, size_t ws_size,
                              hipStream_t stream) {
  const int* iw = (const int*)d_in[0];
  const int* ic = (const int*)d_in[1];
  const int* ip = (const int*)d_in[2];
  const float* mask = (const float*)d_in[3];
  const float* ew = (const float*)d_in[4];
  const float* ec = (const float*)d_in[5];
  const float* ep = (const float*)d_in[6];
  const float* cw = (const float*)d_in[7];
  const float* cb = (const float*)d_in[8];
  const float* wih[3] = {(const float*)d_in[9], (const float*)d_in[12], (const float*)d_in[15]};
  const float* whh[3] = {(const float*)d_in[10], (const float*)d_in[13], (const float*)d_in[16]};
  const float* bs[3] = {(const float*)d_in[11], (const float*)d_in[14], (const float*)d_in[17]};

  char* ws = (char*)d_ws;
  size_t szX0 = (size_t)16384 * 512 * 2;
  size_t szGXf = (size_t)16384 * 2048 * 4;
  size_t szWIH = (size_t)2048 * 512 * 2;
  size_t szWHH = (size_t)2 * 1024 * 256 * 2;
  size_t szPROJ = 60032;
  bool f32gx = ws_size >= szX0 + szGXf + szWIH + szWHH + szPROJ;

  size_t off = 0;
  u16* X0 = (u16*)(ws + off); off += szX0;
  void* GX = (void*)(ws + off); off += f32gx ? szGXf : (szGXf / 2);
  u16* WIHB = (u16*)(ws + off); off += szWIH;
  u16* WHHB = (u16*)(ws + off); off += szWHH;
  u16* PROJ = (u16*)(ws + off);
  u16* X1 = (u16*)d_out;  // bf16 staging in d_out; dead before final f32 write

  hipLaunchKernelGGL(k_proj, dim3(100), dim3(320), 0, stream, ec, cw, PROJ);
  hipLaunchKernelGGL(k_embed, dim3(16384), dim3(512), 0, stream, iw, ip, ew, ep, X0);
  hipLaunchKernelGGL(k_charconv, dim3(1024), dim3(128), 0, stream, ic, PROJ, cb, X0);

  const u16* Xin[3] = {X0, X1, X0};
  void* Xout[3] = {(void*)X1, (void*)X0, d_out};
  int Kin[3] = {500, 512, 512};

  for (int lyr = 0; lyr < 3; lyr++) {
    hipLaunchKernelGGL(k_cvt_wih, dim3(4096), dim3(256), 0, stream, wih[lyr], WIHB, Kin[lyr]);
    hipLaunchKernelGGL(k_cvt_whh, dim3(2048), dim3(256), 0, stream, whh[lyr], WHHB);
    if (f32gx) {
      hipLaunchKernelGGL((k_gemm<true>), dim3(16, 128), dim3(256), 0, stream,
                         Xin[lyr], WIHB, bs[lyr], GX);
      if (lyr < 2)
        hipLaunchKernelGGL((k_recur<true, false>), dim3(8), dim3(512), 0, stream,
                           GX, WHHB, mask, Xout[lyr]);
      else
        hipLaunchKernelGGL((k_recur<true, true>), dim3(8), dim3(512), 0, stream,
                           GX, WHHB, mask, Xout[lyr]);
    } else {
      hipLaunchKernelGGL((k_gemm<false>), dim3(16, 128), dim3(256), 0, stream,
                         Xin[lyr], WIHB, bs[lyr], GX);
      if (lyr < 2)
        hipLaunchKernelGGL((k_recur<false, false>), dim3(8), dim3(512), 0, stream,
                           GX, WHHB, mask, Xout[lyr]);
      else
        hipLaunchKernelGGL((k_recur<false, true>), dim3(8), dim3(512), 0, stream,
                           GX, WHHB, mask, Xout[lyr]);
    }
  }
}

// Round 3
// 3429.029 us; speedup vs baseline: 3.2442x; 3.2442x over previous
//
#include <hip/hip_runtime.h>
#include <cstdint>
#include <cstddef>
#include <type_traits>
#include <utility>

typedef unsigned short u16;
typedef short short8 __attribute__((ext_vector_type(8)));
typedef __bf16 bf16x8 __attribute__((ext_vector_type(8)));
typedef float float4v __attribute__((ext_vector_type(4)));

// ---------- bf16 <-> f32 ----------
__device__ __forceinline__ float bf2f(u16 u) {
  union { uint32_t i; float f; } v; v.i = ((uint32_t)u) << 16; return v.f;
}
__device__ __forceinline__ u16 f2bf(float f) {
  union { uint32_t i; float f; } v; v.f = f;
  uint32_t u = v.i;
  return (u16)((u + 0x7FFFu + ((u >> 16) & 1u)) >> 16);
}

// ---------- fast transcendentals (saturate cleanly at +-inf) ----------
__device__ __forceinline__ float fsig(float x) {
  float e = __expf(-x);
  return __builtin_amdgcn_rcpf(1.0f + e);
}
__device__ __forceinline__ float ftanh(float x) {
  float e = __expf(2.0f * x);
  return 1.0f - 2.0f * __builtin_amdgcn_rcpf(e + 1.0f);
}

// ---------- MFMA wrapper: works whether builtin takes short8 or bf16x8 ----------
template <class V, class = void> struct MfmaTakesShort : std::false_type {};
template <class V>
struct MfmaTakesShort<V, std::void_t<decltype(__builtin_amdgcn_mfma_f32_16x16x32_bf16(
    std::declval<V>(), std::declval<V>(), std::declval<float4v>(), 0, 0, 0))>>
    : std::true_type {};

template <bool UseShort> struct MF {
  template <class V>
  static __device__ __forceinline__ float4v run(V a, V b, float4v c) {
    return __builtin_amdgcn_mfma_f32_16x16x32_bf16(a, b, c, 0, 0, 0);
  }
};
template <> struct MF<false> {
  template <class V>
  static __device__ __forceinline__ float4v run(V a, V b, float4v c) {
    return __builtin_amdgcn_mfma_f32_16x16x32_bf16(
        __builtin_bit_cast(bf16x8, a), __builtin_bit_cast(bf16x8, b), c, 0, 0, 0);
  }
};
__device__ __forceinline__ float4v mfma_bf16(short8 a, short8 b, float4v c) {
  return MF<MfmaTakesShort<short8>::value>::run(a, b, c);
}

// ============================================================================
// Weight conversion: f32 [2048][Kin] -> bf16 [2048][512], zero-padded
// ============================================================================
__global__ void k_cvt_wih(const float* __restrict__ w, u16* __restrict__ o, int Kin) {
  int id = blockIdx.x * 256 + threadIdx.x;   // 2048*512 total
  int n = id >> 9, k = id & 511;
  o[id] = (k < Kin) ? f2bf(w[(long)n * Kin + k]) : (u16)0;
}

// f32 -> bf16 straight convert (w_hh: 2*1024*256 = 524288 elems)
__global__ void k_cvt_whh(const float* __restrict__ w, u16* __restrict__ o) {
  int id = blockIdx.x * 256 + threadIdx.x;
  o[id] = f2bf(w[id]);
}

// ============================================================================
// proj[v][k][nf] = sum_cd emb_char[v][cd] * conv_w[nf][cd][k]   (f32 in, bf16 out)
// ============================================================================
__global__ void k_proj(const float* __restrict__ ec, const float* __restrict__ cw,
                       u16* __restrict__ proj) {
  int v = blockIdx.x, idx = threadIdx.x;
  if (idx >= 300) return;
  int k = idx / 100, nf = idx % 100;
  float s = 0.f;
  for (int cd = 0; cd < 100; cd++)
    s += ec[v * 100 + cd] * cw[(nf * 100 + cd) * 3 + k];
  proj[v * 300 + k * 100 + nf] = f2bf(s);
}

// ============================================================================
// word + pos embedding gather into bf16 x (cols 0..299 word, 400..499 pos,
// 500..511 zero). Char features (300..399) filled by k_charconv.
// ============================================================================
__global__ void k_embed(const int* __restrict__ iw, const int* __restrict__ ip,
                        const float* __restrict__ ew, const float* __restrict__ ep,
                        u16* __restrict__ x) {
  int row = blockIdx.x, j = threadIdx.x;
  u16 v;
  if (j < 300) v = f2bf(ew[(long)iw[row] * 300 + j]);
  else if (j < 400) return;
  else if (j < 500) v = f2bf(ep[ip[row] * 100 + (j - 400)]);
  else v = 0;
  x[row * 512 + j] = v;
}

// ============================================================================
// char conv via proj table in LDS: out[nf] = tanh(b + max_p sum_k proj)
// ============================================================================
__global__ __launch_bounds__(128) void k_charconv(const int* __restrict__ ic,
                                                  const u16* __restrict__ proj,
                                                  const float* __restrict__ cb,
                                                  u16* __restrict__ x) {
  __shared__ u16 pl[30000];
  __shared__ int ids[20];
  int tid = threadIdx.x;
  for (int i = tid; i < 15000; i += 128)
    ((uint32_t*)pl)[i] = ((const uint32_t*)proj)[i];
  float bias = (tid < 100) ? cb[tid] : 0.f;
  for (int r = 0; r < 16; r++) {
    int row = blockIdx.x * 16 + r;
    __syncthreads();  // covers pl load on first iter; protects ids reuse
    if (tid < 20) ids[tid] = ic[row * 20 + tid];
    __syncthreads();
    if (tid < 100) {
      float mx = -1e30f;
      for (int p = 0; p < 22; p++) {
        float s = 0.f;
#pragma unroll
        for (int k = 0; k < 3; k++) {
          int q = p + k - 2;
          if (q >= 0 && q < 20) s += bf2f(pl[ids[q] * 300 + k * 100 + tid]);
        }
        mx = fmaxf(mx, s);
      }
      x[row * 512 + 300 + tid] = f2bf(ftanh(mx + bias));
    }
  }
}

// ============================================================================
// GEMM  C[16384 x 2048] = A[16384 x 512](bf16) @ B[2048 x 512]^T + bias(f32)
// 128x128 tile, BK=64, 4 waves, 16x16x32 MFMA. C fp32 (tier A) or bf16 (tier B).
// ============================================================================
template <bool GXF32>
__global__ __launch_bounds__(256) void k_gemm(const u16* __restrict__ A,
                                              const u16* __restrict__ Bm,
                                              const float* __restrict__ bias,
                                              void* __restrict__ Cv) {
  __shared__ u16 lA[128 * 64];
  __shared__ u16 lB[128 * 64];
  int tid = threadIdx.x;
  int w = tid >> 6, l = tid & 63, q = l >> 4, c16 = l & 15;
  int wm = w >> 1, wn = w & 1;
  int m0 = blockIdx.y * 128, n0 = blockIdx.x * 128;
  float4v acc[4][4];
#pragma unroll
  for (int i = 0; i < 4; i++)
#pragma unroll
    for (int j = 0; j < 4; j++) acc[i][j] = (float4v){0.f, 0.f, 0.f, 0.f};

  for (int kk = 0; kk < 512; kk += 64) {
    __syncthreads();
#pragma unroll
    for (int j = 0; j < 4; j++) {
      int idx = j * 256 + tid;
      int m = idx >> 3, k8 = (idx & 7) * 8;
      *(short8*)(lA + idx * 8) = *(const short8*)(A + (long)(m0 + m) * 512 + kk + k8);
      *(short8*)(lB + idx * 8) = *(const short8*)(Bm + (long)(n0 + m) * 512 + kk + k8);
    }
    __syncthreads();
#pragma unroll
    for (int kt = 0; kt < 2; kt++) {
      short8 af[4], bfv[4];
#pragma unroll
      for (int mt = 0; mt < 4; mt++)
        af[mt] = *(const short8*)(lA + (wm * 64 + mt * 16 + c16) * 64 + kt * 32 + q * 8);
#pragma unroll
      for (int nt = 0; nt < 4; nt++)
        bfv[nt] = *(const short8*)(lB + (wn * 64 + nt * 16 + c16) * 64 + kt * 32 + q * 8);
#pragma unroll
      for (int mt = 0; mt < 4; mt++)
#pragma unroll
        for (int nt = 0; nt < 4; nt++)
          acc[mt][nt] = mfma_bf16(af[mt], bfv[nt], acc[mt][nt]);
    }
  }
#pragma unroll
  for (int mt = 0; mt < 4; mt++)
#pragma unroll
    for (int nt = 0; nt < 4; nt++) {
      int ng = n0 + wn * 64 + nt * 16 + c16;
      float bv = bias[ng];
#pragma unroll
      for (int r = 0; r < 4; r++) {
        long mg = m0 + wm * 64 + mt * 16 + q * 4 + r;
        float val = acc[mt][nt][r] + bv;
        if constexpr (GXF32) ((float*)Cv)[mg * 2048 + ng] = val;
        else ((u16*)Cv)[mg * 2048 + ng] = f2bf(val);
      }
    }
}

// ============================================================================
// LSTM recurrence. 8 blocks = 4 batch-groups x 2 dirs, 512 thr (8 waves).
// Each block owns 16 batch rows end-to-end: zero cross-WG sync.
// w_hh (1024x256 bf16 = 512KB): per wave 46 B-frags in VGPRs + 18 in LDS.
// ALL Breg indices are compile-time constants (full unroll) -> stays in VGPRs.
// gx + mask loads for step s+1 issued right after the nonlinearity consumes
// acc (same registers), hiding HBM latency behind hls-write + barriers.
// ============================================================================
template <bool GXF32, bool OUTF32>
__global__ __launch_bounds__(512, 2) void k_recur(const void* __restrict__ gxv,
                                                  const u16* __restrict__ whh,
                                                  const float* __restrict__ mask,
                                                  void* __restrict__ outv) {
  __shared__ u16 ldsB[8 * 18 * 64 * 8];  // 147456 B
  __shared__ u16 hls[16 * 264];          // 8448 B
  constexpr int NREG = 46;
  int tid = threadIdx.x;
  int w = tid >> 6, l = tid & 63, q = l >> 4, c16 = l & 15;
  int bg = blockIdx.x & 3, d = blockIdx.x >> 2;
  int b0 = bg * 16;
  const u16* Wd = whh + d * (1024 * 256);

  for (int i = tid; i < 16 * 264; i += 512) hls[i] = 0;

  // B fragments: id = f*8 + kt; coltile nt = (f>>1)*16 + 2w + (f&1)
  short8 Breg[NREG];
#pragma unroll
  for (int f = 0; f < 8; f++) {
    int nt = (f >> 1) * 16 + 2 * w + (f & 1);
#pragma unroll
    for (int kt = 0; kt < 8; kt++) {
      int id = f * 8 + kt;
      short8 v = *(const short8*)(Wd + (nt * 16 + c16) * 256 + kt * 32 + q * 8);
      if (id < NREG) Breg[id] = v;
      else *(short8*)(ldsB + ((w * 18 + (id - NREG)) * 64 + l) * 8) = v;
    }
  }
  float c_[2][4], hp[2][4];
#pragma unroll
  for (int i = 0; i < 2; i++)
#pragma unroll
    for (int r = 0; r < 4; r++) { c_[i][r] = 0.f; hp[i][r] = 0.f; }
  __syncthreads();

  const float* gxf = (const float*)gxv;
  const u16* gxh = (const u16*)gxv;
  float* outf = (float*)outv;
  u16* outh = (u16*)outv;

  // ---- peel: preload gx + mask for step 0 ----
  float4v acc[8];
  float m4[4];
  {
    int t0 = d ? 255 : 0;
#pragma unroll
    for (int r = 0; r < 4; r++) m4[r] = mask[(b0 + q * 4 + r) * 256 + t0];
#pragma unroll
    for (int f = 0; f < 8; f++) {
      int n = (((f >> 1) * 16 + 2 * w + (f & 1)) * 16 + c16) + d * 1024;
#pragma unroll
      for (int r = 0; r < 4; r++) {
        long mrow = (long)((b0 + q * 4 + r) * 256 + t0);
        acc[f][r] = GXF32 ? gxf[mrow * 2048 + n] : bf2f(gxh[mrow * 2048 + n]);
      }
    }
  }

#pragma unroll 1
  for (int s = 0; s < 256; s++) {
    int t = d ? (255 - s) : s;
    int sn = (s < 255) ? s + 1 : s;          // next step (clamped; harmless reload)
    int tn = d ? (255 - sn) : sn;

    // gates += h @ w_hh^T   (acc pre-initialized with gx)
#pragma unroll
    for (int kt = 0; kt < 8; kt++) {
      short8 a = *(const short8*)(hls + c16 * 264 + kt * 32 + q * 8);
#pragma unroll
      for (int f = 0; f < 8; f++) {
        int id = f * 8 + kt;
        short8 bb = (id < NREG) ? Breg[id]
                                : *(const short8*)(ldsB + ((w * 18 + (id - NREG)) * 64 + l) * 8);
        acc[f] = mfma_bf16(a, bb, acc[f]);
      }
    }
    // nonlinearity: consumes acc + m4, updates c_/hp
#pragma unroll
    for (int r = 0; r < 4; r++) {
      float mt = m4[r];
#pragma unroll
      for (int hti = 0; hti < 2; hti++) {
        float iv = fsig(acc[0 + hti][r]);
        float fv = fsig(acc[2 + hti][r]);
        float gv = ftanh(acc[4 + hti][r]);
        float ov = fsig(acc[6 + hti][r]);
        float cn = fv * c_[hti][r] + iv * gv;
        float hn = ov * ftanh(cn);
        hn = mt * hn + (1.f - mt) * hp[hti][r];
        cn = mt * cn + (1.f - mt) * c_[hti][r];
        c_[hti][r] = cn;
        hp[hti][r] = hn;
      }
    }
    // ---- prefetch next step's gx + mask into the now-dead acc/m4 regs ----
#pragma unroll
    for (int r = 0; r < 4; r++) m4[r] = mask[(b0 + q * 4 + r) * 256 + tn];
#pragma unroll
    for (int f = 0; f < 8; f++) {
      int n = (((f >> 1) * 16 + 2 * w + (f & 1)) * 16 + c16) + d * 1024;
#pragma unroll
      for (int r = 0; r < 4; r++) {
        long mrow = (long)((b0 + q * 4 + r) * 256 + tn);
        acc[f][r] = GXF32 ? gxf[mrow * 2048 + n] : bf2f(gxh[mrow * 2048 + n]);
      }
    }
    __syncthreads();  // all hls reads complete before overwrite
#pragma unroll
    for (int hti = 0; hti < 2; hti++)
#pragma unroll
      for (int r = 0; r < 4; r++) {
        float hn = hp[hti][r];
        u16 hb = f2bf(hn);
        int colg = (2 * w + hti) * 16 + c16;
        int row = b0 + q * 4 + r;
        hls[(q * 4 + r) * 264 + colg] = hb;
        long oidx = ((long)(row * 256 + t)) * 512 + d * 256 + colg;
        if constexpr (OUTF32) outf[oidx] = hn;
        else outh[oidx] = hb;
      }
    __syncthreads();  // h visible before next step reads
  }
}

// ============================================================================
extern "C" void kernel_launch(void* const* d_in, const int* in_sizes, int n_in,
                              void* d_out, int out_size, void* d_ws, size_t ws_size,
                              hipStream_t stream) {
  const int* iw = (const int*)d_in[0];
  const int* ic = (const int*)d_in[1];
  const int* ip = (const int*)d_in[2];
  const float* mask = (const float*)d_in[3];
  const float* ew = (const float*)d_in[4];
  const float* ec = (const float*)d_in[5];
  const float* ep = (const float*)d_in[6];
  const float* cw = (const float*)d_in[7];
  const float* cb = (const float*)d_in[8];
  const float* wih[3] = {(const float*)d_in[9], (const float*)d_in[12], (const float*)d_in[15]};
  const float* whh[3] = {(const float*)d_in[10], (const float*)d_in[13], (const float*)d_in[16]};
  const float* bs[3] = {(const float*)d_in[11], (const float*)d_in[14], (const float*)d_in[17]};

  char* ws = (char*)d_ws;
  size_t szX0 = (size_t)16384 * 512 * 2;
  size_t szGXf = (size_t)16384 * 2048 * 4;
  size_t szWIH = (size_t)2048 * 512 * 2;
  size_t szWHH = (size_t)2 * 1024 * 256 * 2;
  size_t szPROJ = 60032;
  bool f32gx = ws_size >= szX0 + szGXf + szWIH + szWHH + szPROJ;

  size_t off = 0;
  u16* X0 = (u16*)(ws + off); off += szX0;
  void* GX = (void*)(ws + off); off += f32gx ? szGXf : (szGXf / 2);
  u16* WIHB = (u16*)(ws + off); off += szWIH;
  u16* WHHB = (u16*)(ws + off); off += szWHH;
  u16* PROJ = (u16*)(ws + off);
  u16* X1 = (u16*)d_out;  // bf16 staging in d_out; dead before final f32 write

  hipLaunchKernelGGL(k_proj, dim3(100), dim3(320), 0, stream, ec, cw, PROJ);
  hipLaunchKernelGGL(k_embed, dim3(16384), dim3(512), 0, stream, iw, ip, ew, ep, X0);
  hipLaunchKernelGGL(k_charconv, dim3(1024), dim3(128), 0, stream, ic, PROJ, cb, X0);

  const u16* Xin[3] = {X0, X1, X0};
  void* Xout[3] = {(void*)X1, (void*)X0, d_out};
  int Kin[3] = {500, 512, 512};

  for (int lyr = 0; lyr < 3; lyr++) {
    hipLaunchKernelGGL(k_cvt_wih, dim3(4096), dim3(256), 0, stream, wih[lyr], WIHB, Kin[lyr]);
    hipLaunchKernelGGL(k_cvt_whh, dim3(2048), dim3(256), 0, stream, whh[lyr], WHHB);
    if (f32gx) {
      hipLaunchKernelGGL((k_gemm<true>), dim3(16, 128), dim3(256), 0, stream,
                         Xin[lyr], WIHB, bs[lyr], GX);
      if (lyr < 2)
        hipLaunchKernelGGL((k_recur<true, false>), dim3(8), dim3(512), 0, stream,
                           GX, WHHB, mask, Xout[lyr]);
      else
        hipLaunchKernelGGL((k_recur<true, true>), dim3(8), dim3(512), 0, stream,
                           GX, WHHB, mask, Xout[lyr]);
    } else {
      hipLaunchKernelGGL((k_gemm<false>), dim3(16, 128), dim3(256), 0, stream,
                         Xin[lyr], WIHB, bs[lyr], GX);
      if (lyr < 2)
        hipLaunchKernelGGL((k_recur<false, false>), dim3(8), dim3(512), 0, stream,
                           GX, WHHB, mask, Xout[lyr]);
      else
        hipLaunchKernelGGL((k_recur<false, true>), dim3(8), dim3(512), 0, stream,
                           GX, WHHB, mask, Xout[lyr]);
    }
  }
}

// Round 5
// 3156.135 us; speedup vs baseline: 3.5247x; 1.0865x over previous
//
#include <hip/hip_runtime.h>
#include <cstdint>
#include <cstddef>
#include <type_traits>
#include <utility>

typedef unsigned short u16;
typedef short short8 __attribute__((ext_vector_type(8)));
typedef __bf16 bf16x8 __attribute__((ext_vector_type(8)));
typedef float float4v __attribute__((ext_vector_type(4)));

// ---------- bf16 <-> f32 ----------
__device__ __forceinline__ float bf2f(u16 u) {
  union { uint32_t i; float f; } v; v.i = ((uint32_t)u) << 16; return v.f;
}
__device__ __forceinline__ u16 f2bf(float f) {
  union { uint32_t i; float f; } v; v.f = f;
  uint32_t u = v.i;
  return (u16)((u + 0x7FFFu + ((u >> 16) & 1u)) >> 16);
}

// ---------- fast transcendentals (saturate cleanly at +-inf) ----------
__device__ __forceinline__ float fsig(float x) {
  float e = __expf(-x);
  return __builtin_amdgcn_rcpf(1.0f + e);
}
__device__ __forceinline__ float ftanh(float x) {
  float e = __expf(2.0f * x);
  return 1.0f - 2.0f * __builtin_amdgcn_rcpf(e + 1.0f);
}

// ---------- MFMA wrapper: works whether builtin takes short8 or bf16x8 ----------
template <class V, class = void> struct MfmaTakesShort : std::false_type {};
template <class V>
struct MfmaTakesShort<V, std::void_t<decltype(__builtin_amdgcn_mfma_f32_16x16x32_bf16(
    std::declval<V>(), std::declval<V>(), std::declval<float4v>(), 0, 0, 0))>>
    : std::true_type {};

template <bool UseShort> struct MF {
  template <class V>
  static __device__ __forceinline__ float4v run(V a, V b, float4v c) {
    return __builtin_amdgcn_mfma_f32_16x16x32_bf16(a, b, c, 0, 0, 0);
  }
};
template <> struct MF<false> {
  template <class V>
  static __device__ __forceinline__ float4v run(V a, V b, float4v c) {
    return __builtin_amdgcn_mfma_f32_16x16x32_bf16(
        __builtin_bit_cast(bf16x8, a), __builtin_bit_cast(bf16x8, b), c, 0, 0, 0);
  }
};
__device__ __forceinline__ float4v mfma_bf16(short8 a, short8 b, float4v c) {
  return MF<MfmaTakesShort<short8>::value>::run(a, b, c);
}

// ============================================================================
// Weight conversion: f32 [2048][Kin] -> bf16 [2048][512], zero-padded
// ============================================================================
__global__ void k_cvt_wih(const float* __restrict__ w, u16* __restrict__ o, int Kin) {
  int id = blockIdx.x * 256 + threadIdx.x;   // 2048*512 total
  int n = id >> 9, k = id & 511;
  o[id] = (k < Kin) ? f2bf(w[(long)n * Kin + k]) : (u16)0;
}

// f32 -> bf16 straight convert (w_hh: 2*1024*256 = 524288 elems)
__global__ void k_cvt_whh(const float* __restrict__ w, u16* __restrict__ o) {
  int id = blockIdx.x * 256 + threadIdx.x;
  o[id] = f2bf(w[id]);
}

// ============================================================================
// proj[v][k][nf] = sum_cd emb_char[v][cd] * conv_w[nf][cd][k]   (f32 in, bf16 out)
// ============================================================================
__global__ void k_proj(const float* __restrict__ ec, const float* __restrict__ cw,
                       u16* __restrict__ proj) {
  int v = blockIdx.x, idx = threadIdx.x;
  if (idx >= 300) return;
  int k = idx / 100, nf = idx % 100;
  float s = 0.f;
  for (int cd = 0; cd < 100; cd++)
    s += ec[v * 100 + cd] * cw[(nf * 100 + cd) * 3 + k];
  proj[v * 300 + k * 100 + nf] = f2bf(s);
}

// ============================================================================
// word + pos embedding gather into bf16 x (cols 0..299 word, 400..499 pos,
// 500..511 zero). Char features (300..399) filled by k_charconv.
// ============================================================================
__global__ void k_embed(const int* __restrict__ iw, const int* __restrict__ ip,
                        const float* __restrict__ ew, const float* __restrict__ ep,
                        u16* __restrict__ x) {
  int row = blockIdx.x, j = threadIdx.x;
  u16 v;
  if (j < 300) v = f2bf(ew[(long)iw[row] * 300 + j]);
  else if (j < 400) return;
  else if (j < 500) v = f2bf(ep[ip[row] * 100 + (j - 400)]);
  else v = 0;
  x[row * 512 + j] = v;
}

// ============================================================================
// char conv via proj table in LDS: out[nf] = tanh(b + max_p sum_k proj)
// ============================================================================
__global__ __launch_bounds__(128) void k_charconv(const int* __restrict__ ic,
                                                  const u16* __restrict__ proj,
                                                  const float* __restrict__ cb,
                                                  u16* __restrict__ x) {
  __shared__ u16 pl[30000];
  __shared__ int ids[20];
  int tid = threadIdx.x;
  for (int i = tid; i < 15000; i += 128)
    ((uint32_t*)pl)[i] = ((const uint32_t*)proj)[i];
  float bias = (tid < 100) ? cb[tid] : 0.f;
  for (int r = 0; r < 16; r++) {
    int row = blockIdx.x * 16 + r;
    __syncthreads();  // covers pl load on first iter; protects ids reuse
    if (tid < 20) ids[tid] = ic[row * 20 + tid];
    __syncthreads();
    if (tid < 100) {
      float mx = -1e30f;
      for (int p = 0; p < 22; p++) {
        float s = 0.f;
#pragma unroll
        for (int k = 0; k < 3; k++) {
          int q = p + k - 2;
          if (q >= 0 && q < 20) s += bf2f(pl[ids[q] * 300 + k * 100 + tid]);
        }
        mx = fmaxf(mx, s);
      }
      x[row * 512 + 300 + tid] = f2bf(ftanh(mx + bias));
    }
  }
}

// ============================================================================
// GEMM  C[16384 x 2048] = A[16384 x 512](bf16) @ B[2048 x 512]^T + bias(f32)
// 128x128 tile, BK=64, 4 waves, 16x16x32 MFMA. C fp32 (tier A) or bf16 (tier B).
// ============================================================================
template <bool GXF32>
__global__ __launch_bounds__(256) void k_gemm(const u16* __restrict__ A,
                                              const u16* __restrict__ Bm,
                                              const float* __restrict__ bias,
                                              void* __restrict__ Cv) {
  __shared__ u16 lA[128 * 64];
  __shared__ u16 lB[128 * 64];
  int tid = threadIdx.x;
  int w = tid >> 6, l = tid & 63, q = l >> 4, c16 = l & 15;
  int wm = w >> 1, wn = w & 1;
  int m0 = blockIdx.y * 128, n0 = blockIdx.x * 128;
  float4v acc[4][4];
#pragma unroll
  for (int i = 0; i < 4; i++)
#pragma unroll
    for (int j = 0; j < 4; j++) acc[i][j] = (float4v){0.f, 0.f, 0.f, 0.f};

  for (int kk = 0; kk < 512; kk += 64) {
    __syncthreads();
#pragma unroll
    for (int j = 0; j < 4; j++) {
      int idx = j * 256 + tid;
      int m = idx >> 3, k8 = (idx & 7) * 8;
      *(short8*)(lA + idx * 8) = *(const short8*)(A + (long)(m0 + m) * 512 + kk + k8);
      *(short8*)(lB + idx * 8) = *(const short8*)(Bm + (long)(n0 + m) * 512 + kk + k8);
    }
    __syncthreads();
#pragma unroll
    for (int kt = 0; kt < 2; kt++) {
      short8 af[4], bfv[4];
#pragma unroll
      for (int mt = 0; mt < 4; mt++)
        af[mt] = *(const short8*)(lA + (wm * 64 + mt * 16 + c16) * 64 + kt * 32 + q * 8);
#pragma unroll
      for (int nt = 0; nt < 4; nt++)
        bfv[nt] = *(const short8*)(lB + (wn * 64 + nt * 16 + c16) * 64 + kt * 32 + q * 8);
#pragma unroll
      for (int mt = 0; mt < 4; mt++)
#pragma unroll
        for (int nt = 0; nt < 4; nt++)
          acc[mt][nt] = mfma_bf16(af[mt], bfv[nt], acc[mt][nt]);
    }
  }
#pragma unroll
  for (int mt = 0; mt < 4; mt++)
#pragma unroll
    for (int nt = 0; nt < 4; nt++) {
      int ng = n0 + wn * 64 + nt * 16 + c16;
      float bv = bias[ng];
#pragma unroll
      for (int r = 0; r < 4; r++) {
        long mg = m0 + wm * 64 + mt * 16 + q * 4 + r;
        float val = acc[mt][nt][r] + bv;
        if constexpr (GXF32) ((float*)Cv)[mg * 2048 + ng] = val;
        else ((u16*)Cv)[mg * 2048 + ng] = f2bf(val);
      }
    }
}

// ============================================================================
// LSTM recurrence. 8 blocks = 4 batch-groups x 2 dirs, 512 thr (8 waves).
// Each block owns 16 batch rows end-to-end: zero cross-WG sync.
// w_hh (1024x256 bf16 = 512KB): per wave 46 B-frags resident (intrinsic path,
// AGPR-eligible) + 18 in LDS. Step split into two fully-unrolled hti halves so
// only acc[4] (16 regs) is live during MFMA: peak ~234 regs <= 256/wave cap
// (8-wave block => 2 waves/SIMD => 512-reg pool/SIMD).
// All Breg indices compile-time constants. No inline asm (R4 NaN: MFMA-in-asm
// defeats the hazard recognizer -> VALU read of acc inside hazard window).
// hp re-read from hls (exact when mask==1; bf16-stable when mask==0).
// ============================================================================
template <bool GXF32, bool OUTF32>
__global__ __launch_bounds__(512, 2) void k_recur(const void* __restrict__ gxv,
                                                  const u16* __restrict__ whh,
                                                  const float* __restrict__ mask,
                                                  void* __restrict__ outv) {
  __shared__ u16 ldsB[8 * 18 * 64 * 8];  // 147456 B
  __shared__ u16 hls[16 * 264];          // 8448 B (pad kills b128 bank conflicts)
  constexpr int NREG = 46;
  int tid = threadIdx.x;
  int w = tid >> 6, l = tid & 63, q = l >> 4, c16 = l & 15;
  int bg = blockIdx.x & 3, d = blockIdx.x >> 2;
  int b0 = bg * 16;
  const u16* Wd = whh + d * (1024 * 256);

  for (int i = tid; i < 16 * 264; i += 512) hls[i] = 0;

  // B fragments: id = f*8 + kt, f = g*2 + hti; coltile nt = g*16 + 2w + hti
  short8 Breg[NREG];
#pragma unroll
  for (int f = 0; f < 8; f++) {
    int nt = (f >> 1) * 16 + 2 * w + (f & 1);
#pragma unroll
    for (int kt = 0; kt < 8; kt++) {
      int id = f * 8 + kt;
      short8 v = *(const short8*)(Wd + (nt * 16 + c16) * 256 + kt * 32 + q * 8);
      if (id < NREG) Breg[id] = v;
      else *(short8*)(ldsB + ((w * 18 + (id - NREG)) * 64 + l) * 8) = v;
    }
  }
  float c_[2][4];
#pragma unroll
  for (int i = 0; i < 2; i++)
#pragma unroll
    for (int r = 0; r < 4; r++) c_[i][r] = 0.f;
  __syncthreads();

  const float* gxf = (const float*)gxv;
  const u16* gxh = (const u16*)gxv;
  float* outf = (float*)outv;
  u16* outh = (u16*)outv;

  // step-invariant per-lane element offsets (row-major GX), row = b0+q*4+r
  int rb[4];
#pragma unroll
  for (int r = 0; r < 4; r++)
    rb[r] = (b0 + q * 4 + r) * 524288 + 2 * w * 16 + c16;

#pragma unroll 1
  for (int s = 0; s < 256; s++) {
    int t = d ? (255 - s) : s;

    float m4[4];
#pragma unroll
    for (int r = 0; r < 4; r++) m4[r] = mask[(b0 + q * 4 + r) * 256 + t];

    const float* gxs = gxf + (size_t)t * 2048 + d * 1024;
    const u16* gxsh = gxh + (size_t)t * 2048 + d * 1024;

    unsigned hnp[4];  // packed bf16 hn staging: [hti*2 + (r>>1)], halves by r&1

#pragma unroll
    for (int hti = 0; hti < 2; hti++) {
      // acc init = gx (C operand). col = (g*16 + 2w + hti)*16 + c16
      float4v acc[4];
#pragma unroll
      for (int g = 0; g < 4; g++) {
        int goff = g * 256 + hti * 16;  // compile-time const
#pragma unroll
        for (int r = 0; r < 4; r++)
          acc[g][r] = GXF32 ? gxs[(size_t)rb[r] + goff]
                            : bf2f(gxsh[(size_t)rb[r] + goff]);
      }
      // gates += h @ w_hh^T for this hti (all indices compile-time)
#pragma unroll
      for (int kt = 0; kt < 8; kt++) {
        short8 a = *(const short8*)(hls + c16 * 264 + kt * 32 + q * 8);
#pragma unroll
        for (int g = 0; g < 4; g++) {
          int id = (g * 2 + hti) * 8 + kt;
          short8 bb = (id < NREG)
                          ? Breg[id]
                          : *(const short8*)(ldsB + ((w * 18 + (id - NREG)) * 64 + l) * 8);
          acc[g] = mfma_bf16(a, bb, acc[g]);
        }
      }
      // nonlinearity for this hti; hp read back from hls
      unsigned p0 = 0u, p1 = 0u;
#pragma unroll
      for (int r = 0; r < 4; r++) {
        float mt = m4[r];
        float iv = fsig(acc[0][r]);
        float fv = fsig(acc[1][r]);
        float gv = ftanh(acc[2][r]);
        float ov = fsig(acc[3][r]);
        int colg = (2 * w + hti) * 16 + c16;
        float hpo = bf2f(hls[(q * 4 + r) * 264 + colg]);
        float cn = fv * c_[hti][r] + iv * gv;
        float hn = ov * ftanh(cn);
        hn = mt * hn + (1.f - mt) * hpo;
        cn = mt * cn + (1.f - mt) * c_[hti][r];
        c_[hti][r] = cn;
        int row = b0 + q * 4 + r;
        long oidx = ((long)(row * 256 + t)) * 512 + d * 256 + colg;
        if constexpr (OUTF32) outf[oidx] = hn;
        else outh[oidx] = f2bf(hn);
        unsigned hb = (unsigned)f2bf(hn) << ((r & 1) * 16);
        if (r < 2) p0 |= hb; else p1 |= hb;
      }
      hnp[hti * 2 + 0] = p0;
      hnp[hti * 2 + 1] = p1;
    }
    __syncthreads();  // all hls reads (a-frags + hp, both halves) complete
#pragma unroll
    for (int hti = 0; hti < 2; hti++)
#pragma unroll
      for (int r = 0; r < 4; r++) {
        u16 hb = (u16)(hnp[hti * 2 + (r >> 1)] >> ((r & 1) * 16));
        hls[(q * 4 + r) * 264 + (2 * w + hti) * 16 + c16] = hb;
      }
    __syncthreads();  // h visible before next step reads
  }
}

// ============================================================================
extern "C" void kernel_launch(void* const* d_in, const int* in_sizes, int n_in,
                              void* d_out, int out_size, void* d_ws, size_t ws_size,
                              hipStream_t stream) {
  const int* iw = (const int*)d_in[0];
  const int* ic = (const int*)d_in[1];
  const int* ip = (const int*)d_in[2];
  const float* mask = (const float*)d_in[3];
  const float* ew = (const float*)d_in[4];
  const float* ec = (const float*)d_in[5];
  const float* ep = (const float*)d_in[6];
  const float* cw = (const float*)d_in[7];
  const float* cb = (const float*)d_in[8];
  const float* wih[3] = {(const float*)d_in[9], (const float*)d_in[12], (const float*)d_in[15]};
  const float* whh[3] = {(const float*)d_in[10], (const float*)d_in[13], (const float*)d_in[16]};
  const float* bs[3] = {(const float*)d_in[11], (const float*)d_in[14], (const float*)d_in[17]};

  char* ws = (char*)d_ws;
  size_t szX0 = (size_t)16384 * 512 * 2;
  size_t szGXf = (size_t)16384 * 2048 * 4;
  size_t szWIH = (size_t)2048 * 512 * 2;
  size_t szWHH = (size_t)2 * 1024 * 256 * 2;
  size_t szPROJ = 60032;
  bool f32gx = ws_size >= szX0 + szGXf + szWIH + szWHH + szPROJ;

  size_t off = 0;
  u16* X0 = (u16*)(ws + off); off += szX0;
  void* GX = (void*)(ws + off); off += f32gx ? szGXf : (szGXf / 2);
  u16* WIHB = (u16*)(ws + off); off += szWIH;
  u16* WHHB = (u16*)(ws + off); off += szWHH;
  u16* PROJ = (u16*)(ws + off);
  u16* X1 = (u16*)d_out;  // bf16 staging in d_out; dead before final f32 write

  hipLaunchKernelGGL(k_proj, dim3(100), dim3(320), 0, stream, ec, cw, PROJ);
  hipLaunchKernelGGL(k_embed, dim3(16384), dim3(512), 0, stream, iw, ip, ew, ep, X0);
  hipLaunchKernelGGL(k_charconv, dim3(1024), dim3(128), 0, stream, ic, PROJ, cb, X0);

  const u16* Xin[3] = {X0, X1, X0};
  void* Xout[3] = {(void*)X1, (void*)X0, d_out};
  int Kin[3] = {500, 512, 512};

  for (int lyr = 0; lyr < 3; lyr++) {
    hipLaunchKernelGGL(k_cvt_wih, dim3(4096), dim3(256), 0, stream, wih[lyr], WIHB, Kin[lyr]);
    hipLaunchKernelGGL(k_cvt_whh, dim3(2048), dim3(256), 0, stream, whh[lyr], WHHB);
    if (f32gx) {
      hipLaunchKernelGGL((k_gemm<true>), dim3(16, 128), dim3(256), 0, stream,
                         Xin[lyr], WIHB, bs[lyr], GX);
      if (lyr < 2)
        hipLaunchKernelGGL((k_recur<true, false>), dim3(8), dim3(512), 0, stream,
                           GX, WHHB, mask, Xout[lyr]);
      else
        hipLaunchKernelGGL((k_recur<true, true>), dim3(8), dim3(512), 0, stream,
                           GX, WHHB, mask, Xout[lyr]);
    } else {
      hipLaunchKernelGGL((k_gemm<false>), dim3(16, 128), dim3(256), 0, stream,
                         Xin[lyr], WIHB, bs[lyr], GX);
      if (lyr < 2)
        hipLaunchKernelGGL((k_recur<false, false>), dim3(8), dim3(512), 0, stream,
                           GX, WHHB, mask, Xout[lyr]);
      else
        hipLaunchKernelGGL((k_recur<false, true>), dim3(8), dim3(512), 0, stream,
                           GX, WHHB, mask, Xout[lyr]);
    }
  }
}